// Round 1
// baseline (964.562 us; speedup 1.0000x reference)
//
#include <hip/hip_runtime.h>
#include <stdint.h>

#define BATCH 65536
#define FDIM 512
#define HDIM 256
#define NC 10
#define NREP 16

typedef short short8 __attribute__((ext_vector_type(8)));
typedef float f32x4 __attribute__((ext_vector_type(4)));

// ---- workspace layout (bytes) ----
#define OFF_FC0T   ((size_t)0)
#define OFF_FC1T   (OFF_FC0T + (size_t)512*512*2)
#define OFF_WT     (OFF_FC1T + (size_t)512*512*2)
#define OFF_X4     (OFF_WT   + (size_t)256*512*2)
#define OFF_ACC    (OFF_X4   + (size_t)BATCH*512*2)
// accumulator region (floats):
#define SCAL_SUMSQ 0
#define SCAL_CE    16
#define SCAL_ACC   32
#define SCAL_L1    48
#define SCAL_VAR   64
#define SCAL_N     128
#define CNT_OFF    SCAL_N                 // NREP*16 floats
#define GSUM_OFF   (SCAL_N + NREP*16)     // NREP*5120 floats
#define ACC_FLOATS (GSUM_OFF + NREP*5120)

__device__ __forceinline__ unsigned short f2b(float f){
  unsigned u = __float_as_uint(f);
  u += 0x7FFFu + ((u >> 16) & 1u);
  return (unsigned short)(u >> 16);
}
__device__ __forceinline__ float b2f(unsigned short h){
  return __uint_as_float(((unsigned)h) << 16);
}

__global__ void k_zero(float* p, int n){
  int i = blockIdx.x*blockDim.x + threadIdx.x;
  int stride = gridDim.x*blockDim.x;
  for (; i < n; i += stride) p[i] = 0.f;
}

// transpose weights to bf16 [n][k] + L1 reduction
__global__ void k_prep(const float* __restrict__ fc0, const float* __restrict__ fc1,
                       const float* __restrict__ w,   const float* __restrict__ w1,
                       unsigned short* __restrict__ fc0T, unsigned short* __restrict__ fc1T,
                       unsigned short* __restrict__ wT,   float* __restrict__ scal){
  int i = blockIdx.x*256 + threadIdx.x;
  float l1v = 0.f;
  if (i < 262144){
    float v = fc0[(i & 511)*512 + (i >> 9)];
    fc0T[i] = f2b(v); l1v = fabsf(v);
  } else if (i < 524288){
    int j = i - 262144;
    float v = fc1[(j & 511)*512 + (j >> 9)];
    fc1T[j] = f2b(v); l1v = fabsf(v);
  } else if (i < 655360){
    int j = i - 524288;
    float v = w[(j & 511)*256 + (j >> 9)];
    wT[j] = f2b(v); l1v = fabsf(v);
  } else if (i < 657920){
    float v = w1[i - 655360]; l1v = fabsf(v);
  }
  for (int off = 32; off; off >>= 1) l1v += __shfl_down(l1v, off);
  if ((threadIdx.x & 63) == 0 && l1v != 0.f)
    atomicAdd(&scal[SCAL_L1 + (blockIdx.x & (NREP-1))], l1v);
}

// K1: x1 = x@fc0, x2 = relu(x@fc1), x4 = x + (1+sigmoid(x1))*x2  -> ws (bf16)
// also accumulates sumsq(x4)
__global__ __launch_bounds__(256) void k_gemm12(
    const float* __restrict__ x,
    const unsigned short* __restrict__ fc0T,
    const unsigned short* __restrict__ fc1T,
    unsigned short* __restrict__ x4out,
    float* __restrict__ scal)
{
  __shared__ __align__(16) unsigned short As[64][88];
  __shared__ __align__(16) unsigned short Bs0[64][88];
  __shared__ __align__(16) unsigned short Bs1[64][88];
  __shared__ float red[4];

  int blk = blockIdx.x;
  int xcd = blk & 7, s = blk >> 3;
  int rowtile = xcd*128 + (s >> 3);   // same-rowtile blocks stay on one XCD
  int colblk = s & 7;
  int r0 = rowtile*64, n0 = colblk*64;

  int t = threadIdx.x;
  int wv = t >> 6, lane = t & 63, ln = lane & 15, quad = lane >> 4;

  const f32x4 zv = {0.f,0.f,0.f,0.f};
  f32x4 acc1[4], acc2[4];
  #pragma unroll
  for (int nt = 0; nt < 4; ++nt){ acc1[nt] = zv; acc2[nt] = zv; }

  for (int kt = 0; kt < 8; ++kt){
    int k0 = kt*64;
    #pragma unroll
    for (int i = 0; i < 4; ++i){
      int idx = t + i*256;               // 0..1023
      int row = idx >> 4, c4 = (idx & 15)*4;
      float4 v = *(const float4*)(x + (size_t)(r0+row)*FDIM + k0 + c4);
      ushort4 o; o.x=f2b(v.x); o.y=f2b(v.y); o.z=f2b(v.z); o.w=f2b(v.w);
      *(ushort4*)&As[row][c4] = o;
    }
    #pragma unroll
    for (int i = 0; i < 4; ++i){
      int idx = t + i*256;
      int row = idx >> 4, c4 = (idx & 15)*4;
      *(ushort4*)&Bs0[row][c4] = *(const ushort4*)(fc0T + (size_t)(n0+row)*FDIM + k0 + c4);
      *(ushort4*)&Bs1[row][c4] = *(const ushort4*)(fc1T + (size_t)(n0+row)*FDIM + k0 + c4);
    }
    __syncthreads();
    #pragma unroll
    for (int k2 = 0; k2 < 2; ++k2){
      int kk = k2*32 + quad*8;
      short8 a = *(const short8*)&As[wv*16 + ln][kk];
      #pragma unroll
      for (int nt = 0; nt < 4; ++nt){
        short8 b0 = *(const short8*)&Bs0[nt*16 + ln][kk];
        acc1[nt] = __builtin_amdgcn_mfma_f32_16x16x32_bf16(a, b0, acc1[nt], 0, 0, 0);
        short8 b1 = *(const short8*)&Bs1[nt*16 + ln][kk];
        acc2[nt] = __builtin_amdgcn_mfma_f32_16x16x32_bf16(a, b1, acc2[nt], 0, 0, 0);
      }
    }
    __syncthreads();
  }

  float sumsq = 0.f;
  #pragma unroll
  for (int nt = 0; nt < 4; ++nt){
    #pragma unroll
    for (int r = 0; r < 4; ++r){
      int row = wv*16 + quad*4 + r;
      int col = n0 + nt*16 + ln;
      size_t gi = (size_t)(r0+row)*FDIM + col;
      float xv  = x[gi];                        // exact fp32 residual
      float x1v = acc1[nt][r];
      float x2v = fmaxf(acc2[nt][r], 0.f);
      float gate = 1.f + 1.f/(1.f + __expf(-x1v));
      float x4 = fmaf(gate, x2v, xv);
      unsigned short ub = f2b(x4);
      float fq = b2f(ub);                       // consistent with stored value
      sumsq = fmaf(fq, fq, sumsq);
      x4out[gi] = ub;
    }
  }
  for (int off = 32; off; off >>= 1) sumsq += __shfl_down(sumsq, off);
  if (lane == 0) red[wv] = sumsq;
  __syncthreads();
  if (t == 0)
    atomicAdd(&scal[SCAL_SUMSQ + (blk & (NREP-1))], red[0]+red[1]+red[2]+red[3]);
}

// K2: h = relu(x4@w); logits = h@w1; CE/argmax/acc; class sums of x4
__global__ __launch_bounds__(256) void k_gemm3_head(
    const unsigned short* __restrict__ x4,
    const int* __restrict__ y,
    const unsigned short* __restrict__ wT,
    const float* __restrict__ w1,
    float* __restrict__ scal,
    float* __restrict__ gcnt,
    float* __restrict__ gsum)
{
  __shared__ __align__(16) unsigned short As[64][40];
  __shared__ __align__(16) unsigned short Wsh[256][40];
  __shared__ float csum[NC*512];
  __shared__ int ys[64];

  int blk = blockIdx.x;
  int r0 = blk * 64;
  int t = threadIdx.x;
  int wv = t >> 6, lane = t & 63, ln = lane & 15, quad = lane >> 4;
  int rep = blk & (NREP-1);

  if (t < 64) ys[t] = y[r0 + t];
  for (int i = t; i < NC*512; i += 256) csum[i] = 0.f;
  __syncthreads();

  if (t < NC){
    int c = 0;
    for (int r = 0; r < 64; ++r) c += (ys[r] == t) ? 1 : 0;
    atomicAdd(&gcnt[rep*16 + t], (float)c);
  }

  const f32x4 zv = {0.f,0.f,0.f,0.f};
  f32x4 acch[16];
  #pragma unroll
  for (int jt = 0; jt < 16; ++jt) acch[jt] = zv;

  for (int kt = 0; kt < 16; ++kt){
    int k0 = kt*32;
    #pragma unroll
    for (int i = 0; i < 2; ++i){
      int idx = t + i*256;
      int row = idx >> 3, c4 = (idx & 7)*4;
      *(ushort4*)&As[row][c4] = *(const ushort4*)(x4 + (size_t)(r0+row)*FDIM + k0 + c4);
    }
    #pragma unroll
    for (int i = 0; i < 8; ++i){
      int idx = t + i*256;
      int row = idx >> 3, c4 = (idx & 7)*4;
      *(ushort4*)&Wsh[row][c4] = *(const ushort4*)(wT + (size_t)row*FDIM + k0 + c4);
    }
    __syncthreads();
    // class sums from staged x4 tile
    #pragma unroll
    for (int i = 0; i < 8; ++i){
      int e = t + i*256;
      int row = e >> 5, col = e & 31;
      atomicAdd(&csum[ys[row]*512 + k0 + col], b2f(As[row][col]));
    }
    int kk = quad*8;
    short8 a = *(const short8*)&As[wv*16 + ln][kk];
    #pragma unroll
    for (int jt = 0; jt < 16; ++jt){
      short8 b = *(const short8*)&Wsh[jt*16 + ln][kk];
      acch[jt] = __builtin_amdgcn_mfma_f32_16x16x32_bf16(a, b, acch[jt], 0, 0, 0);
    }
    __syncthreads();
  }

  for (int i = t; i < NC*512; i += 256)
    atomicAdd(&gsum[(size_t)rep*5120 + i], csum[i]);

  // head: logits per row, CE + argmax
  float part[4][10];
  #pragma unroll
  for (int r=0;r<4;++r)
    #pragma unroll
    for (int c=0;c<10;++c) part[r][c]=0.f;
  #pragma unroll
  for (int jt = 0; jt < 16; ++jt){
    int col = jt*16 + ln;
    float wv1[10];
    #pragma unroll
    for (int c=0;c<10;++c) wv1[c] = w1[col*10 + c];
    #pragma unroll
    for (int r=0;r<4;++r){
      float hv = fmaxf(acch[jt][r], 0.f);
      #pragma unroll
      for (int c=0;c<10;++c) part[r][c] = fmaf(hv, wv1[c], part[r][c]);
    }
  }
  #pragma unroll
  for (int m = 1; m < 16; m <<= 1){
    #pragma unroll
    for (int r=0;r<4;++r)
      #pragma unroll
      for (int c=0;c<10;++c)
        part[r][c] += __shfl_xor(part[r][c], m);
  }
  float ce_l = 0.f, acc_l = 0.f;
  if (ln == 0){
    #pragma unroll
    for (int r=0;r<4;++r){
      int row = wv*16 + quad*4 + r;
      int yv = ys[row];
      float best = part[r][0]; int bi = 0;
      #pragma unroll
      for (int c=1;c<10;++c){ if (part[r][c] > best){ best = part[r][c]; bi = c; } }
      float se = 0.f;
      #pragma unroll
      for (int c=0;c<10;++c) se += __expf(part[r][c] - best);
      float lse = best + __logf(se);
      ce_l += (lse - part[r][yv]);
      acc_l += (bi == yv) ? 1.f : 0.f;
    }
  }
  ce_l  += __shfl_down(ce_l, 16);
  acc_l += __shfl_down(acc_l, 16);
  ce_l  += __shfl_down(ce_l, 32);
  acc_l += __shfl_down(acc_l, 32);
  if (lane == 0){
    atomicAdd(&scal[SCAL_CE  + rep], ce_l);
    atomicAdd(&scal[SCAL_ACC + rep], acc_l);
  }
}

__global__ void k_reduce(const float* __restrict__ gsum, const float* __restrict__ gcnt,
                         float* __restrict__ scal){
  int idx = blockIdx.x*256 + threadIdx.x;  // 0..5119
  float S = 0.f;
  for (int r = 0; r < NREP; ++r) S += gsum[(size_t)r*5120 + idx];
  int c = idx >> 9;
  float cnt = 0.f;
  for (int r = 0; r < NREP; ++r) cnt += gcnt[r*16 + c];
  float contrib = S*S / fmaxf(cnt, 1.f);
  for (int off = 32; off; off >>= 1) contrib += __shfl_down(contrib, off);
  __shared__ float red[4];
  if ((threadIdx.x & 63) == 0) red[threadIdx.x >> 6] = contrib;
  __syncthreads();
  if (threadIdx.x == 0) atomicAdd(&scal[SCAL_VAR], red[0]+red[1]+red[2]+red[3]);
}

__global__ void k_final(const float* __restrict__ scal, float* __restrict__ out){
  if (threadIdx.x == 0 && blockIdx.x == 0){
    float sumsq=0.f, ce=0.f, acc=0.f, l1=0.f;
    for (int r=0;r<NREP;++r){
      sumsq += scal[SCAL_SUMSQ+r];
      ce    += scal[SCAL_CE+r];
      acc   += scal[SCAL_ACC+r];
      l1    += scal[SCAL_L1+r];
    }
    float var_loss = sumsq - scal[SCAL_VAR];
    float loss = ce/(float)BATCH + 1e-4f*l1 + 1e-3f*var_loss;
    out[0] = loss;
    out[1] = acc/(float)BATCH;
  }
}

extern "C" void kernel_launch(void* const* d_in, const int* in_sizes, int n_in,
                              void* d_out, int out_size, void* d_ws, size_t ws_size,
                              hipStream_t stream){
  (void)in_sizes; (void)n_in; (void)out_size; (void)ws_size;
  const float* x   = (const float*)d_in[0];
  const int*   y   = (const int*)d_in[1];
  const float* fc0 = (const float*)d_in[2];
  const float* fc1 = (const float*)d_in[3];
  const float* w   = (const float*)d_in[4];
  const float* w1  = (const float*)d_in[5];
  char* ws = (char*)d_ws;
  unsigned short* fc0T = (unsigned short*)(ws + OFF_FC0T);
  unsigned short* fc1T = (unsigned short*)(ws + OFF_FC1T);
  unsigned short* wT   = (unsigned short*)(ws + OFF_WT);
  unsigned short* x4   = (unsigned short*)(ws + OFF_X4);
  float* accb = (float*)(ws + OFF_ACC);
  float* scal = accb;
  float* gcnt = accb + CNT_OFF;
  float* gsum = accb + GSUM_OFF;

  k_zero<<<161, 512, 0, stream>>>(accb, ACC_FLOATS);
  k_prep<<<2570, 256, 0, stream>>>(fc0, fc1, w, w1, fc0T, fc1T, wT, scal);
  k_gemm12<<<8192, 256, 0, stream>>>(x, fc0T, fc1T, x4, scal);
  k_gemm3_head<<<1024, 256, 0, stream>>>(x4, y, wT, w1, scal, gcnt, gsum);
  k_reduce<<<20, 256, 0, stream>>>(gsum, gcnt, scal);
  k_final<<<1, 64, 0, stream>>>(scal, (float*)d_out);
}

// Round 2
// 451.576 us; speedup vs baseline: 2.1360x; 2.1360x over previous
//
#include <hip/hip_runtime.h>
#include <stdint.h>

#define BATCH 65536
#define FDIM 512
#define HDIM 256
#define NC 10
#define NREP 16

typedef short short8 __attribute__((ext_vector_type(8)));
typedef float f32x4 __attribute__((ext_vector_type(4)));

// ---- workspace layout (bytes) ----  (total ~65.9 MB, same footprint as R1)
#define OFF_FC0T   ((size_t)0)                          // 512x512 bf16 tiled
#define OFF_FC1T   (OFF_FC0T + (size_t)512*512*2)
#define OFF_WT     (OFF_FC1T + (size_t)512*512*2)       // 256x512 bf16 tiled
#define OFF_X4     (OFF_WT   + (size_t)256*512*2)       // 65536x512 bf16 row-major
#define OFF_ACC    (OFF_X4   + (size_t)BATCH*512*2)
// accumulator region (floats):
#define SCAL_SUMSQ 0
#define SCAL_CE    16
#define SCAL_ACC   32
#define SCAL_L1    48
#define SCAL_VAR   64
#define SCAL_N     128
#define CNT_OFF    SCAL_N                 // NREP*16 floats
#define GSUM_OFF   (SCAL_N + NREP*16)     // NREP*5120 floats
#define ACC_FLOATS (GSUM_OFF + NREP*5120)

#define GLL(g,l) __builtin_amdgcn_global_load_lds((const __attribute__((address_space(1))) void*)(g), (__attribute__((address_space(3))) void*)(l), 16, 0, 0)

__device__ __forceinline__ unsigned short f2b(float f){
  unsigned u = __float_as_uint(f);
  u += 0x7FFFu + ((u >> 16) & 1u);
  return (unsigned short)(u >> 16);
}
__device__ __forceinline__ float b2f(unsigned short h){
  return __uint_as_float(((unsigned)h) << 16);
}
// pack bf16(f0) | bf16(f1)<<16 via v_perm (round-half-up, 3 VALU ops)
__device__ __forceinline__ unsigned pk2b(float f0, float f1){
  unsigned u0 = __float_as_uint(f0) + 0x8000u;
  unsigned u1 = __float_as_uint(f1) + 0x8000u;
  return __builtin_amdgcn_perm(u1, u0, 0x07060302u);
}

__global__ void k_zero(float* p, int n){
  int i = blockIdx.x*blockDim.x + threadIdx.x;
  int stride = gridDim.x*blockDim.x;
  for (; i < n; i += stride) p[i] = 0.f;
}

// Tiled (MFMA-fragment-order) weight layout:
// tile (J = n/16, C = k/32) is 1KB at ((J*Kt + C)*1024); within the tile,
// lane slot l = (n&15) | (((k>>3)&3)<<4) holds 8 bf16 of k = (l>>4)*8..+7.
__global__ void k_prep(const float* __restrict__ fc0, const float* __restrict__ fc1,
                       const float* __restrict__ w,   const float* __restrict__ w1,
                       unsigned short* __restrict__ fc0T, unsigned short* __restrict__ fc1T,
                       unsigned short* __restrict__ wT,   float* __restrict__ scal){
  int i = blockIdx.x*256 + threadIdx.x;
  float l1v = 0.f;
  if (i < 32768){                       // fc0 [k][n=512]
    int n4 = i&15, m = (i>>4)&3, C = (i>>6)&15, J = i>>10;
    int n = J*16+n4, k8 = C*4+m;
    unsigned short o[8];
    #pragma unroll
    for (int j=0;j<8;++j){ float v = fc0[(size_t)(k8*8+j)*512 + n]; o[j]=f2b(v); l1v += fabsf(v); }
    *(short8*)&fc0T[(size_t)(J*16+C)*512 + (i&63)*8] = *(short8*)o;
  } else if (i < 65536){                // fc1
    int j0 = i - 32768;
    int n4 = j0&15, m = (j0>>4)&3, C = (j0>>6)&15, J = j0>>10;
    int n = J*16+n4, k8 = C*4+m;
    unsigned short o[8];
    #pragma unroll
    for (int j=0;j<8;++j){ float v = fc1[(size_t)(k8*8+j)*512 + n]; o[j]=f2b(v); l1v += fabsf(v); }
    *(short8*)&fc1T[(size_t)(J*16+C)*512 + (j0&63)*8] = *(short8*)o;
  } else if (i < 81920){                // w [k][n=256]
    int j0 = i - 65536;
    int n4 = j0&15, m = (j0>>4)&3, C = (j0>>6)&15, J = j0>>10;
    int n = J*16+n4, k8 = C*4+m;
    unsigned short o[8];
    #pragma unroll
    for (int j=0;j<8;++j){ float v = w[(size_t)(k8*8+j)*256 + n]; o[j]=f2b(v); l1v += fabsf(v); }
    *(short8*)&wT[(size_t)(J*16+C)*512 + (j0&63)*8] = *(short8*)o;
  } else if (i < 82240){                // w1 L1 only
    int j0 = (i - 81920)*8;
    #pragma unroll
    for (int j=0;j<8;++j) l1v += fabsf(w1[j0+j]);
  }
  for (int off = 32; off; off >>= 1) l1v += __shfl_down(l1v, off);
  if ((threadIdx.x & 63) == 0 && l1v != 0.f)
    atomicAdd(&scal[SCAL_L1 + (blockIdx.x & (NREP-1))], l1v);
}

// K1: x1=x@fc0, x2=relu(x@fc1), x4 = x + (1+sigmoid(x1))*x2 -> bf16 row-major; sumsq(x4)
// 128 rows x 64 cols per block; 4 waves 2x2; per k32 per wave: 4A+4B ds_read, 16 MFMA
__global__ __launch_bounds__(256) void k_gemm12(
    const float* __restrict__ x,
    const unsigned short* __restrict__ fc0T,
    const unsigned short* __restrict__ fc1T,
    unsigned short* __restrict__ x4out,
    float* __restrict__ scal)
{
  __shared__ __align__(16) unsigned short As[128*72];   // padded row-major bf16 A
  __shared__ __align__(16) unsigned short Bs0[4096];    // 8 tiles (4 J x 2 C) of 1KB
  __shared__ __align__(16) unsigned short Bs1[4096];
  __shared__ float red[4];

  int blk = blockIdx.x;
  int xcd = blk & 7, s = blk >> 3;
  int rowblk = xcd*64 + (s >> 3);   // 8 col-blocks of a row-block share one XCD
  int colblk = s & 7;
  int r0 = rowblk*128, c0 = colblk*64;

  int t = threadIdx.x;
  int wv = t >> 6, lane = t & 63, ln = lane & 15, quad = lane >> 4;
  int wr = wv >> 1, wc = wv & 1;

  const f32x4 zv = {0.f,0.f,0.f,0.f};
  f32x4 acc1[4][2], acc2[4][2];
  #pragma unroll
  for (int rt=0;rt<4;++rt){ acc1[rt][0]=zv; acc1[rt][1]=zv; acc2[rt][0]=zv; acc2[rt][1]=zv; }

  for (int kt = 0; kt < 8; ++kt){
    // ---- A staging: fp32 -> bf16 (packed perm convert) into padded LDS ----
    #pragma unroll
    for (int i = 0; i < 4; ++i){
      int idx = t + i*256;                    // 0..1023 = 128 rows x 8 col-chunks
      int row = idx >> 3, c8 = idx & 7;
      const float* src = x + (size_t)(r0+row)*FDIM + kt*64 + c8*8;
      float4 v0 = *(const float4*)src;
      float4 v1 = *(const float4*)(src+4);
      unsigned o[4];
      o[0] = pk2b(v0.x, v0.y); o[1] = pk2b(v0.z, v0.w);
      o[2] = pk2b(v1.x, v1.y); o[3] = pk2b(v1.z, v1.w);
      *(short8*)&As[row*72 + c8*8] = *(short8*)o;
    }
    // ---- B staging: global_load_lds width 16, fragment-tiled ----
    {
      const char* g0 = (const char*)fc0T + (((size_t)(colblk*4 + wv)*16 + kt*2) << 10) + lane*16;
      const char* g1 = (const char*)fc1T + (((size_t)(colblk*4 + wv)*16 + kt*2) << 10) + lane*16;
      GLL(g0,        (char*)Bs0 + ((wv*2+0) << 10));
      GLL(g0 + 1024, (char*)Bs0 + ((wv*2+1) << 10));
      GLL(g1,        (char*)Bs1 + ((wv*2+0) << 10));
      GLL(g1 + 1024, (char*)Bs1 + ((wv*2+1) << 10));
    }
    __syncthreads();
    #pragma unroll
    for (int c = 0; c < 2; ++c){
      short8 a[4];
      #pragma unroll
      for (int rt=0;rt<4;++rt)
        a[rt] = *(const short8*)&As[(wr*64 + rt*16 + ln)*72 + c*32 + quad*8];
      #pragma unroll
      for (int ct=0;ct<2;++ct){
        int jl = wc*2 + ct;
        short8 b0 = *(const short8*)&Bs0[(jl*2+c)*512 + lane*8];
        #pragma unroll
        for (int rt=0;rt<4;++rt)
          acc1[rt][ct] = __builtin_amdgcn_mfma_f32_16x16x32_bf16(a[rt], b0, acc1[rt][ct], 0,0,0);
        short8 b1 = *(const short8*)&Bs1[(jl*2+c)*512 + lane*8];
        #pragma unroll
        for (int rt=0;rt<4;++rt)
          acc2[rt][ct] = __builtin_amdgcn_mfma_f32_16x16x32_bf16(a[rt], b1, acc2[rt][ct], 0,0,0);
      }
    }
    __syncthreads();
  }

  // ---- epilogue: gate + exact fp32 residual, sumsq, LDS transpose, coalesced store ----
  float sumsq = 0.f;
  #pragma unroll
  for (int rt=0;rt<4;++rt){
    #pragma unroll
    for (int ct=0;ct<2;++ct){
      #pragma unroll
      for (int r=0;r<4;++r){
        int row_l = wr*64 + rt*16 + quad*4 + r;
        int col_l = wc*32 + ct*16 + ln;
        float xv  = x[(size_t)(r0+row_l)*FDIM + c0 + col_l];   // L1/L2-hot
        float x1v = acc1[rt][ct][r];
        float x2v = fmaxf(acc2[rt][ct][r], 0.f);
        float gate = 1.f + 1.f/(1.f + __expf(-x1v));
        float x4v = fmaf(gate, x2v, xv);
        unsigned short ub = f2b(x4v);
        float fq = b2f(ub);
        sumsq = fmaf(fq, fq, sumsq);
        As[row_l*72 + col_l] = ub;   // reuse As as transpose buffer
      }
    }
  }
  for (int off = 32; off; off >>= 1) sumsq += __shfl_down(sumsq, off);
  if (lane == 0) red[wv] = sumsq;
  __syncthreads();
  if (t == 0)
    atomicAdd(&scal[SCAL_SUMSQ + (blk & (NREP-1))], red[0]+red[1]+red[2]+red[3]);
  // readback + 16B stores
  {
    int row = t >> 1, hf = t & 1;
    #pragma unroll
    for (int j=0;j<4;++j){
      short8 v = *(const short8*)&As[row*72 + hf*32 + j*8];
      *(short8*)&x4out[(size_t)(r0+row)*FDIM + c0 + hf*32 + j*8] = v;
    }
  }
}

// class sums of x4 (row-major) via predicated register accumulation
__global__ __launch_bounds__(256) void k_csum(const unsigned short* __restrict__ x4,
                                              const int* __restrict__ y,
                                              float* __restrict__ gsum){
  int blk = blockIdx.x;             // 512 blocks x 128 rows
  int t = threadIdx.x;              // cols 2t, 2t+1
  int r0 = blk*128;
  float a0[NC], a1[NC];
  #pragma unroll
  for (int c=0;c<NC;++c){ a0[c]=0.f; a1[c]=0.f; }
  for (int row=0; row<128; ++row){
    int yv = y[r0+row];
    unsigned v = *(const unsigned*)&x4[(size_t)(r0+row)*FDIM + t*2];
    float lo = b2f((unsigned short)(v & 0xffff));
    float hi = b2f((unsigned short)(v >> 16));
    #pragma unroll
    for (int c=0;c<NC;++c){
      bool m = (yv == c);
      a0[c] += m ? lo : 0.f;
      a1[c] += m ? hi : 0.f;
    }
  }
  int rep = blk & (NREP-1);
  #pragma unroll
  for (int c=0;c<NC;++c){
    atomicAdd(&gsum[(size_t)rep*5120 + c*512 + t*2    ], a0[c]);
    atomicAdd(&gsum[(size_t)rep*5120 + c*512 + t*2 + 1], a1[c]);
  }
}

// K2a: h = relu(x4 @ w) -> bf16, stored in the low 512B of each x4 row (stride 512 shorts)
// 128 rows x 256 cols per block, 512 threads, 8 waves (2 row x 4 col)
__global__ __launch_bounds__(512) void k_gemm3(
    const unsigned short* __restrict__ x4,
    const unsigned short* __restrict__ wT,
    unsigned short* __restrict__ hout)
{
  __shared__ __align__(16) char lds[51200];
  unsigned short* As = (unsigned short*)lds;            // [128][72] = 18432 B
  unsigned short* Bs = (unsigned short*)(lds + 18432);  // 32 tiles x 1KB
  unsigned short* trans = (unsigned short*)lds;         // reuse: [128][136] = 34816 B

  int blk = blockIdx.x;
  int r0 = blk * 128;
  int t = threadIdx.x;
  int wv = t >> 6, lane = t & 63, ln = lane & 15, quad = lane >> 4;
  int wr = wv >> 2, wc = wv & 3;

  const f32x4 zv = {0.f,0.f,0.f,0.f};
  f32x4 acc[4][4];
  #pragma unroll
  for (int rt=0;rt<4;++rt)
    #pragma unroll
    for (int ct=0;ct<4;++ct) acc[rt][ct] = zv;

  for (int kt = 0; kt < 8; ++kt){
    #pragma unroll
    for (int i = 0; i < 2; ++i){
      int idx = t + i*512;                 // 0..1023
      int row = idx >> 3, c8 = idx & 7;
      short8 v = *(const short8*)&x4[(size_t)(r0+row)*FDIM + kt*64 + c8*8];
      *(short8*)&As[row*72 + c8*8] = v;
    }
    {
      const char* g = (const char*)wT + (((size_t)(wv*2)*16 + kt*2) << 10) + lane*16;
      GLL(g,          (char*)Bs + ((wv*4+0) << 10));
      GLL(g + 1024,   (char*)Bs + ((wv*4+1) << 10));
      GLL(g + 16384,  (char*)Bs + ((wv*4+2) << 10));   // J = wv*2+1 (16 k-tiles * 1KB)
      GLL(g + 17408,  (char*)Bs + ((wv*4+3) << 10));
    }
    __syncthreads();
    #pragma unroll
    for (int c = 0; c < 2; ++c){
      short8 a[4];
      #pragma unroll
      for (int rt=0;rt<4;++rt)
        a[rt] = *(const short8*)&As[(wr*64 + rt*16 + ln)*72 + c*32 + quad*8];
      #pragma unroll
      for (int ct=0;ct<4;++ct){
        short8 b = *(const short8*)&Bs[((wc*4+ct)*2+c)*512 + lane*8];
        #pragma unroll
        for (int rt=0;rt<4;++rt)
          acc[rt][ct] = __builtin_amdgcn_mfma_f32_16x16x32_bf16(a[rt], b, acc[rt][ct], 0,0,0);
      }
    }
    __syncthreads();
  }

  // epilogue: relu -> bf16, two 128-col halves through LDS transpose
  #pragma unroll
  for (int hf = 0; hf < 2; ++hf){
    __syncthreads();
    if ((wc >> 1) == hf){
      #pragma unroll
      for (int rt=0;rt<4;++rt)
        #pragma unroll
        for (int ct=0;ct<4;++ct)
          #pragma unroll
          for (int r=0;r<4;++r){
            int row_l = wr*64 + rt*16 + quad*4 + r;
            int col_h = (wc & 1)*64 + ct*16 + ln;
            trans[row_l*136 + col_h] = f2b(fmaxf(acc[rt][ct][r], 0.f));
          }
    }
    __syncthreads();
    int row = t >> 2, cq = (t & 3)*32;
    #pragma unroll
    for (int j=0;j<4;++j){
      short8 v = *(const short8*)&trans[row*136 + cq + j*8];
      *(short8*)&hout[(size_t)(r0+row)*512 + hf*128 + cq + j*8] = v;
    }
  }
}

// K2b: logits = relu-free (h already relu'd) h @ w1; CE, argmax/acc, class counts
__global__ __launch_bounds__(256) void k_head(
    const unsigned short* __restrict__ h,   // stride 512 shorts per row, 256 valid
    const int* __restrict__ y,
    const float* __restrict__ w1,
    float* __restrict__ scal, float* __restrict__ gcnt)
{
  __shared__ float w1s[2560];
  __shared__ float cnt[NC];
  __shared__ float redc[4], reda[4];
  int t = threadIdx.x;
  int row = blockIdx.x*256 + t;
  int rep = blockIdx.x & (NREP-1);
  for (int i=t;i<2560;i+=256) w1s[i] = w1[i];
  if (t < NC) cnt[t] = 0.f;
  __syncthreads();
  int yv = y[row];
  atomicAdd(&cnt[yv], 1.f);
  float part[NC];
  #pragma unroll
  for (int c=0;c<NC;++c) part[c]=0.f;
  for (int j8=0;j8<32;++j8){
    short8 hv8 = *(const short8*)&h[(size_t)row*512 + j8*8];
    #pragma unroll
    for (int jj=0;jj<8;++jj){
      float hv = b2f((unsigned short)hv8[jj]);
      #pragma unroll
      for (int c=0;c<NC;++c) part[c] = fmaf(hv, w1s[(j8*8+jj)*10 + c], part[c]);
    }
  }
  float best = part[0]; int bi = 0;
  #pragma unroll
  for (int c=1;c<NC;++c){ if (part[c] > best){ best = part[c]; bi = c; } }
  float se = 0.f;
  #pragma unroll
  for (int c=0;c<NC;++c) se += __expf(part[c] - best);
  float lse = best + __logf(se);
  float py = part[0];
  #pragma unroll
  for (int c=1;c<NC;++c) py = (yv == c) ? part[c] : py;
  float ce = lse - py;
  float ac = (bi == yv) ? 1.f : 0.f;
  for (int off = 32; off; off >>= 1){ ce += __shfl_down(ce, off); ac += __shfl_down(ac, off); }
  int lane = t & 63, wv = t >> 6;
  if (lane == 0){ redc[wv] = ce; reda[wv] = ac; }
  __syncthreads();
  if (t == 0){
    atomicAdd(&scal[SCAL_CE  + rep], redc[0]+redc[1]+redc[2]+redc[3]);
    atomicAdd(&scal[SCAL_ACC + rep], reda[0]+reda[1]+reda[2]+reda[3]);
  }
  if (t < NC) atomicAdd(&gcnt[rep*16 + t], cnt[t]);
}

__global__ void k_reduce(const float* __restrict__ gsum, const float* __restrict__ gcnt,
                         float* __restrict__ scal){
  int idx = blockIdx.x*256 + threadIdx.x;  // 0..5119
  float S = 0.f;
  for (int r = 0; r < NREP; ++r) S += gsum[(size_t)r*5120 + idx];
  int c = idx >> 9;
  float cntv = 0.f;
  for (int r = 0; r < NREP; ++r) cntv += gcnt[r*16 + c];
  float contrib = S*S / fmaxf(cntv, 1.f);
  for (int off = 32; off; off >>= 1) contrib += __shfl_down(contrib, off);
  __shared__ float red[4];
  if ((threadIdx.x & 63) == 0) red[threadIdx.x >> 6] = contrib;
  __syncthreads();
  if (threadIdx.x == 0) atomicAdd(&scal[SCAL_VAR], red[0]+red[1]+red[2]+red[3]);
}

__global__ void k_final(const float* __restrict__ scal, float* __restrict__ out){
  if (threadIdx.x == 0 && blockIdx.x == 0){
    float sumsq=0.f, ce=0.f, acc=0.f, l1=0.f;
    for (int r=0;r<NREP;++r){
      sumsq += scal[SCAL_SUMSQ+r];
      ce    += scal[SCAL_CE+r];
      acc   += scal[SCAL_ACC+r];
      l1    += scal[SCAL_L1+r];
    }
    float var_loss = sumsq - scal[SCAL_VAR];
    float loss = ce/(float)BATCH + 1e-4f*l1 + 1e-3f*var_loss;
    out[0] = loss;
    out[1] = acc/(float)BATCH;
  }
}

extern "C" void kernel_launch(void* const* d_in, const int* in_sizes, int n_in,
                              void* d_out, int out_size, void* d_ws, size_t ws_size,
                              hipStream_t stream){
  (void)in_sizes; (void)n_in; (void)out_size; (void)ws_size;
  const float* x   = (const float*)d_in[0];
  const int*   y   = (const int*)d_in[1];
  const float* fc0 = (const float*)d_in[2];
  const float* fc1 = (const float*)d_in[3];
  const float* w   = (const float*)d_in[4];
  const float* w1  = (const float*)d_in[5];
  char* ws = (char*)d_ws;
  unsigned short* fc0T = (unsigned short*)(ws + OFF_FC0T);
  unsigned short* fc1T = (unsigned short*)(ws + OFF_FC1T);
  unsigned short* wT   = (unsigned short*)(ws + OFF_WT);
  unsigned short* x4   = (unsigned short*)(ws + OFF_X4);
  float* accb = (float*)(ws + OFF_ACC);
  float* scal = accb;
  float* gcnt = accb + CNT_OFF;
  float* gsum = accb + GSUM_OFF;

  k_zero<<<161, 512, 0, stream>>>(accb, ACC_FLOATS);
  k_prep<<<322, 256, 0, stream>>>(fc0, fc1, w, w1, fc0T, fc1T, wT, scal);
  k_gemm12<<<4096, 256, 0, stream>>>(x, fc0T, fc1T, x4, scal);
  k_csum<<<512, 256, 0, stream>>>(x4, y, gsum);              // must run before k_gemm3 (h aliases x4 rows)
  k_gemm3<<<512, 512, 0, stream>>>(x4, wT, x4 /*hout in-place, low half of each row*/);
  k_head<<<256, 256, 0, stream>>>(x4, y, w1, scal, gcnt);
  k_reduce<<<20, 256, 0, stream>>>(gsum, gcnt, scal);
  k_final<<<1, 64, 0, stream>>>(scal, (float*)d_out);
}

// Round 3
// 435.232 us; speedup vs baseline: 2.2162x; 1.0376x over previous
//
#include <hip/hip_runtime.h>
#include <stdint.h>

#define BATCH 65536
#define FDIM 512
#define HDIM 256
#define NC 10
#define NREP 16

typedef short short8 __attribute__((ext_vector_type(8)));
typedef float f32x4 __attribute__((ext_vector_type(4)));

// ---- workspace layout (bytes) ----
// Tiled layout everywhere: tile (I=row/16, C=k/32) is 1KB at (I*nC + C)*1024;
// lane slot l = (row&15) | (((k>>3)&3)<<4) holds 8 bf16 (k = (l>>4)*8 .. +7).
#define OFF_FC0T   ((size_t)0)                          // 32 J x 16 C tiles
#define OFF_FC1T   (OFF_FC0T + (size_t)512*512*2)
#define OFF_WT     (OFF_FC1T + (size_t)512*512*2)       // 16 J x 16 C tiles
#define OFF_XT     (OFF_WT   + (size_t)256*512*2)       // 4096 I x 16 C (64MB); h (32MB) aliases after gemm12
#define OFF_X4T    (OFF_XT   + (size_t)BATCH*512*2)     // 4096 I x 16 C (64MB)
#define OFF_ACC    (OFF_X4T  + (size_t)BATCH*512*2)
#define SCAL_SUMSQ 0
#define SCAL_CE    16
#define SCAL_ACC   32
#define SCAL_L1    48
#define SCAL_VAR   64
#define SCAL_N     128
#define CNT_OFF    SCAL_N                 // NREP*16 floats
#define GSUM_OFF   (SCAL_N + NREP*16)     // NREP*5120 floats
#define ACC_FLOATS (GSUM_OFF + NREP*5120)

#define GLL(g,l) __builtin_amdgcn_global_load_lds((const __attribute__((address_space(1))) void*)(g), (__attribute__((address_space(3))) void*)(l), 16, 0, 0)

__device__ __forceinline__ unsigned short f2b(float f){
  unsigned u = __float_as_uint(f);
  u += 0x7FFFu + ((u >> 16) & 1u);
  return (unsigned short)(u >> 16);
}
__device__ __forceinline__ float b2f(unsigned short h){
  return __uint_as_float(((unsigned)h) << 16);
}
__device__ __forceinline__ unsigned pk2b(float f0, float f1){
  unsigned u0 = __float_as_uint(f0) + 0x8000u;
  unsigned u1 = __float_as_uint(f1) + 0x8000u;
  return __builtin_amdgcn_perm(u1, u0, 0x07060302u);
}

__global__ void k_zero(float* p, int n){
  int i = blockIdx.x*blockDim.x + threadIdx.x;
  int stride = gridDim.x*blockDim.x;
  for (; i < n; i += stride) p[i] = 0.f;
}

// weights -> tiled bf16 + L1 reduction
__global__ void k_prep(const float* __restrict__ fc0, const float* __restrict__ fc1,
                       const float* __restrict__ w,   const float* __restrict__ w1,
                       unsigned short* __restrict__ fc0T, unsigned short* __restrict__ fc1T,
                       unsigned short* __restrict__ wT,   float* __restrict__ scal){
  int i = blockIdx.x*256 + threadIdx.x;
  float l1v = 0.f;
  if (i < 32768){                       // fc0 [k][512]
    int n4 = i&15, m = (i>>4)&3, C = (i>>6)&15, J = i>>10;
    int n = J*16+n4, k8 = C*4+m;
    unsigned short o[8];
    #pragma unroll
    for (int j=0;j<8;++j){ float v = fc0[(size_t)(k8*8+j)*512 + n]; o[j]=f2b(v); l1v += fabsf(v); }
    *(short8*)&fc0T[(size_t)(J*16+C)*512 + (i&63)*8] = *(short8*)o;
  } else if (i < 65536){                // fc1
    int j0 = i - 32768;
    int n4 = j0&15, m = (j0>>4)&3, C = (j0>>6)&15, J = j0>>10;
    int n = J*16+n4, k8 = C*4+m;
    unsigned short o[8];
    #pragma unroll
    for (int j=0;j<8;++j){ float v = fc1[(size_t)(k8*8+j)*512 + n]; o[j]=f2b(v); l1v += fabsf(v); }
    *(short8*)&fc1T[(size_t)(J*16+C)*512 + (j0&63)*8] = *(short8*)o;
  } else if (i < 81920){                // w [k][256]
    int j0 = i - 65536;
    int n4 = j0&15, m = (j0>>4)&3, C = (j0>>6)&15, J = j0>>10;
    int n = J*16+n4, k8 = C*4+m;
    unsigned short o[8];
    #pragma unroll
    for (int j=0;j<8;++j){ float v = w[(size_t)(k8*8+j)*256 + n]; o[j]=f2b(v); l1v += fabsf(v); }
    *(short8*)&wT[(size_t)(J*16+C)*512 + (j0&63)*8] = *(short8*)o;
  } else if (i < 82240){                // w1 L1 only
    int j0 = (i - 81920)*8;
    #pragma unroll
    for (int j=0;j<8;++j) l1v += fabsf(w1[j0+j]);
  }
  for (int off = 32; off; off >>= 1) l1v += __shfl_down(l1v, off);
  if ((threadIdx.x & 63) == 0 && l1v != 0.f)
    atomicAdd(&scal[SCAL_L1 + (blockIdx.x & (NREP-1))], l1v);
}

// x fp32 -> tiled bf16; one wave per I-tile
__global__ __launch_bounds__(256) void k_xcast(const float* __restrict__ x,
                                               unsigned short* __restrict__ xT){
  int I = blockIdx.x*4 + (threadIdx.x >> 6);
  int l = threadIdx.x & 63;
  int row = I*16 + (l & 15), q = l >> 4;
  const float* src = x + (size_t)row*FDIM + q*8;
  #pragma unroll
  for (int C = 0; C < 16; ++C){
    float4 v0 = *(const float4*)(src + C*32);
    float4 v1 = *(const float4*)(src + C*32 + 4);
    unsigned o[4];
    o[0] = pk2b(v0.x, v0.y); o[1] = pk2b(v0.z, v0.w);
    o[2] = pk2b(v1.x, v1.y); o[3] = pk2b(v1.z, v1.w);
    *(short8*)&xT[(((size_t)I*16 + C) << 9) + l*8] = *(short8*)o;
  }
}

// K1: pure-GLL dual GEMM. Block = 128 rows x 64 cols; 4 waves (2r x 2c), wave 64x32.
__global__ __launch_bounds__(256) void k_gemm12(
    const unsigned short* __restrict__ xT,
    const unsigned short* __restrict__ fc0T,
    const unsigned short* __restrict__ fc1T,
    unsigned short* __restrict__ x4T,
    float* __restrict__ scal)
{
  __shared__ __align__(16) char lds[32768];
  unsigned short* As    = (unsigned short*)lds;           // 16 x 1KB tiles
  unsigned short* Bs0   = (unsigned short*)(lds + 16384); // 8 x 1KB
  unsigned short* Bs1   = (unsigned short*)(lds + 24576); // 8 x 1KB
  unsigned short* trans = (unsigned short*)(lds + 16384); // epilogue reuse, 16KB
  __shared__ float red[4];

  int blk = blockIdx.x;
  int xcd = blk & 7, s = blk >> 3;
  int rowblk = xcd*64 + (s >> 3);
  int colblk = s & 7;

  int t = threadIdx.x;
  int wv = t >> 6, lane = t & 63, ln = lane & 15, quad = lane >> 4;
  int wr = wv >> 1, wc = wv & 1;

  const f32x4 zv = {0.f,0.f,0.f,0.f};
  f32x4 acc1[4][2], acc2[4][2];
  #pragma unroll
  for (int rt=0;rt<4;++rt){ acc1[rt][0]=zv; acc1[rt][1]=zv; acc2[rt][0]=zv; acc2[rt][1]=zv; }

  const char* xb  = (const char*)xT;
  const char* b0b = (const char*)fc0T;
  const char* b1b = (const char*)fc1T;

  for (int kt = 0; kt < 8; ++kt){
    #pragma unroll
    for (int i = 0; i < 2; ++i)
      #pragma unroll
      for (int c = 0; c < 2; ++c){
        size_t Ig = (size_t)(rowblk*8 + wv*2 + i);
        GLL(xb + ((Ig*16 + kt*2 + c) << 10) + lane*16,
            (char*)As + (((wv*2+i)*2 + c) << 10));
      }
    {
      size_t Jg = (size_t)(colblk*4 + wv);
      const char* g0 = b0b + ((Jg*16 + kt*2) << 10) + lane*16;
      const char* g1 = b1b + ((Jg*16 + kt*2) << 10) + lane*16;
      GLL(g0,        (char*)Bs0 + ((wv*2+0) << 10));
      GLL(g0 + 1024, (char*)Bs0 + ((wv*2+1) << 10));
      GLL(g1,        (char*)Bs1 + ((wv*2+0) << 10));
      GLL(g1 + 1024, (char*)Bs1 + ((wv*2+1) << 10));
    }
    __syncthreads();
    #pragma unroll
    for (int c = 0; c < 2; ++c){
      short8 a[4];
      #pragma unroll
      for (int rt=0;rt<4;++rt)
        a[rt] = *(const short8*)&As[(((wr*4+rt)*2 + c) << 9) + lane*8];
      #pragma unroll
      for (int ct=0;ct<2;++ct){
        int jl = wc*2 + ct;
        short8 b0 = *(const short8*)&Bs0[((jl*2+c) << 9) + lane*8];
        #pragma unroll
        for (int rt=0;rt<4;++rt)
          acc1[rt][ct] = __builtin_amdgcn_mfma_f32_16x16x32_bf16(a[rt], b0, acc1[rt][ct], 0,0,0);
        short8 b1 = *(const short8*)&Bs1[((jl*2+c) << 9) + lane*8];
        #pragma unroll
        for (int rt=0;rt<4;++rt)
          acc2[rt][ct] = __builtin_amdgcn_mfma_f32_16x16x32_bf16(a[rt], b1, acc2[rt][ct], 0,0,0);
      }
    }
    __syncthreads();
  }

  // re-stage this block's own column-slice of x for the residual (bf16)
  #pragma unroll
  for (int i = 0; i < 2; ++i)
    #pragma unroll
    for (int c = 0; c < 2; ++c){
      size_t Ig = (size_t)(rowblk*8 + wv*2 + i);
      GLL(xb + ((Ig*16 + colblk*2 + c) << 10) + lane*16,
          (char*)As + (((wv*2+i)*2 + c) << 10));
    }
  __syncthreads();

  float sumsq = 0.f;
  #pragma unroll
  for (int rt=0;rt<4;++rt){
    #pragma unroll
    for (int ct=0;ct<2;++ct){
      int slot_hi = (ct*2 + (ln>>3)) << 4;
      int elem = ln & 7;
      #pragma unroll
      for (int r=0;r<4;++r){
        int addr = (((wr*4+rt)*2 + wc) << 9) + ((quad*4+r) | slot_hi)*8 + elem;
        float xv  = b2f(As[addr]);
        float x1v = acc1[rt][ct][r];
        float x2v = fmaxf(acc2[rt][ct][r], 0.f);
        float gate = 1.f + 1.f/(1.f + __expf(-x1v));
        float x4v = fmaf(gate, x2v, xv);
        unsigned short ub = f2b(x4v);
        float fq = b2f(ub);
        sumsq = fmaf(fq, fq, sumsq);
        trans[addr] = ub;           // identical tiled position in x4
      }
    }
  }
  for (int off = 32; off; off >>= 1) sumsq += __shfl_down(sumsq, off);
  if (lane == 0) red[wv] = sumsq;
  __syncthreads();
  if (t == 0)
    atomicAdd(&scal[SCAL_SUMSQ + (blk & (NREP-1))], red[0]+red[1]+red[2]+red[3]);
  {
    int lt = t >> 4;                       // local tile 0..15
    int I_local = lt >> 1, C_local = lt & 1;
    size_t gbase = ((size_t)(rowblk*8 + I_local)*16 + colblk*2 + C_local) << 9;
    int s0 = (t & 15)*32;
    #pragma unroll
    for (int j=0;j<4;++j)
      *(short8*)&x4T[gbase + s0 + j*8] = *(const short8*)&trans[(lt << 9) + s0 + j*8];
  }
}

// class sums from tiled x4: one wave per (C-phase, 64 I-tiles)
__global__ __launch_bounds__(256) void k_csum(const unsigned short* __restrict__ x4T,
                                              const int* __restrict__ y,
                                              float* __restrict__ gsum){
  int w = blockIdx.x*4 + (threadIdx.x >> 6);   // 1024 waves
  int l = threadIdx.x & 63;
  int C = w & 15, Ig = w >> 4;                 // Ig 0..63
  int rl = l & 15, q = l >> 4;
  float a[NC][8];
  #pragma unroll
  for (int c=0;c<NC;++c)
    #pragma unroll
    for (int e=0;e<8;++e) a[c][e]=0.f;
  for (int ii = 0; ii < 64; ++ii){
    int I = Ig*64 + ii;
    int yv = y[I*16 + rl];
    short8 v = *(const short8*)&x4T[(((size_t)I*16 + C) << 9) + l*8];
    float f[8];
    #pragma unroll
    for (int e=0;e<8;++e) f[e] = b2f((unsigned short)v[e]);
    #pragma unroll
    for (int c=0;c<NC;++c){
      bool m = (yv == c);
      #pragma unroll
      for (int e=0;e<8;++e) a[c][e] += m ? f[e] : 0.f;
    }
  }
  #pragma unroll
  for (int off = 1; off < 16; off <<= 1)
    #pragma unroll
    for (int c=0;c<NC;++c)
      #pragma unroll
      for (int e=0;e<8;++e) a[c][e] += __shfl_xor(a[c][e], off);
  if (rl == 0){
    int rep = Ig & (NREP-1);
    int kb = C*32 + q*8;
    #pragma unroll
    for (int c=0;c<NC;++c)
      #pragma unroll
      for (int e=0;e<8;++e)
        atomicAdd(&gsum[(size_t)rep*5120 + c*512 + kb + e], a[c][e]);
  }
}

// K2a: h = relu(x4 @ w) -> bf16 row-major [B][256]. Block 128 x 256, 8 waves 2x4.
__global__ __launch_bounds__(512) void k_gemm3(
    const unsigned short* __restrict__ x4T,
    const unsigned short* __restrict__ wT,
    unsigned short* __restrict__ h)
{
  __shared__ __align__(16) char lds[49152];
  unsigned short* As    = (unsigned short*)lds;            // 16 x 1KB
  unsigned short* Bs    = (unsigned short*)(lds + 16384);  // 32 x 1KB
  unsigned short* trans = (unsigned short*)lds;            // [128][136] reuse

  int blk = blockIdx.x;
  int t = threadIdx.x;
  int wv = t >> 6, lane = t & 63, ln = lane & 15, quad = lane >> 4;
  int wr = wv >> 2, wc = wv & 3;

  const f32x4 zv = {0.f,0.f,0.f,0.f};
  f32x4 acc[4][4];
  #pragma unroll
  for (int rt=0;rt<4;++rt)
    #pragma unroll
    for (int ct=0;ct<4;++ct) acc[rt][ct] = zv;

  const char* ab = (const char*)x4T;
  const char* bb = (const char*)wT;

  for (int kt = 0; kt < 8; ++kt){
    {
      size_t Ig = (size_t)(blk*8 + wv);
      GLL(ab + ((Ig*16 + kt*2 + 0) << 10) + lane*16, (char*)As + ((wv*2+0) << 10));
      GLL(ab + ((Ig*16 + kt*2 + 1) << 10) + lane*16, (char*)As + ((wv*2+1) << 10));
    }
    #pragma unroll
    for (int i = 0; i < 2; ++i)
      #pragma unroll
      for (int c = 0; c < 2; ++c){
        size_t Jg = (size_t)(wv*2 + i);
        GLL(bb + ((Jg*16 + kt*2 + c) << 10) + lane*16,
            (char*)Bs + (((wv*2+i)*2 + c) << 10));
      }
    __syncthreads();
    #pragma unroll
    for (int c = 0; c < 2; ++c){
      short8 a[4];
      #pragma unroll
      for (int rt=0;rt<4;++rt)
        a[rt] = *(const short8*)&As[(((wr*4+rt)*2 + c) << 9) + lane*8];
      #pragma unroll
      for (int ct=0;ct<4;++ct){
        short8 b = *(const short8*)&Bs[(((wc*4+ct)*2 + c) << 9) + lane*8];
        #pragma unroll
        for (int rt=0;rt<4;++rt)
          acc[rt][ct] = __builtin_amdgcn_mfma_f32_16x16x32_bf16(a[rt], b, acc[rt][ct], 0,0,0);
      }
    }
    __syncthreads();
  }

  #pragma unroll
  for (int hf = 0; hf < 2; ++hf){
    __syncthreads();
    if ((wc >> 1) == hf){
      #pragma unroll
      for (int rt=0;rt<4;++rt)
        #pragma unroll
        for (int ct=0;ct<4;++ct)
          #pragma unroll
          for (int r=0;r<4;++r){
            int row_l = wr*64 + rt*16 + quad*4 + r;
            int col_h = (wc & 1)*64 + ct*16 + ln;
            trans[row_l*136 + col_h] = f2b(fmaxf(acc[rt][ct][r], 0.f));
          }
    }
    __syncthreads();
    int row = t >> 2, cq = (t & 3)*32;
    #pragma unroll
    for (int j=0;j<4;++j){
      short8 v = *(const short8*)&trans[row*136 + cq + j*8];
      *(short8*)&h[(size_t)(blk*128+row)*HDIM + hf*128 + cq + j*8] = v;
    }
  }
}

// K2b: logits = h @ w1; CE, argmax/acc, class counts
__global__ __launch_bounds__(256) void k_head(
    const unsigned short* __restrict__ h,   // row-major stride 256
    const int* __restrict__ y,
    const float* __restrict__ w1,
    float* __restrict__ scal, float* __restrict__ gcnt)
{
  __shared__ float w1s[2560];
  __shared__ float cnt[NC];
  __shared__ float redc[4], reda[4];
  int t = threadIdx.x;
  int row = blockIdx.x*256 + t;
  int rep = blockIdx.x & (NREP-1);
  for (int i=t;i<2560;i+=256) w1s[i] = w1[i];
  if (t < NC) cnt[t] = 0.f;
  __syncthreads();
  int yv = y[row];
  atomicAdd(&cnt[yv], 1.f);
  float part[NC];
  #pragma unroll
  for (int c=0;c<NC;++c) part[c]=0.f;
  for (int j8=0;j8<32;++j8){
    short8 hv8 = *(const short8*)&h[(size_t)row*HDIM + j8*8];
    #pragma unroll
    for (int jj=0;jj<8;++jj){
      float hv = b2f((unsigned short)hv8[jj]);
      #pragma unroll
      for (int c=0;c<NC;++c) part[c] = fmaf(hv, w1s[(j8*8+jj)*10 + c], part[c]);
    }
  }
  float best = part[0]; int bi = 0;
  #pragma unroll
  for (int c=1;c<NC;++c){ if (part[c] > best){ best = part[c]; bi = c; } }
  float se = 0.f;
  #pragma unroll
  for (int c=0;c<NC;++c) se += __expf(part[c] - best);
  float lse = best + __logf(se);
  float py = part[0];
  #pragma unroll
  for (int c=1;c<NC;++c) py = (yv == c) ? part[c] : py;
  float ce = lse - py;
  float ac = (bi == yv) ? 1.f : 0.f;
  for (int off = 32; off; off >>= 1){ ce += __shfl_down(ce, off); ac += __shfl_down(ac, off); }
  int lane = t & 63, wvv = t >> 6;
  if (lane == 0){ redc[wvv] = ce; reda[wvv] = ac; }
  __syncthreads();
  if (t == 0){
    atomicAdd(&scal[SCAL_CE  + rep], redc[0]+redc[1]+redc[2]+redc[3]);
    atomicAdd(&scal[SCAL_ACC + rep], reda[0]+reda[1]+reda[2]+reda[3]);
  }
  if (t < NC) atomicAdd(&gcnt[rep*16 + t], cnt[t]);
}

__global__ void k_reduce(const float* __restrict__ gsum, const float* __restrict__ gcnt,
                         float* __restrict__ scal){
  int idx = blockIdx.x*256 + threadIdx.x;  // 0..5119
  float S = 0.f;
  for (int r = 0; r < NREP; ++r) S += gsum[(size_t)r*5120 + idx];
  int c = idx >> 9;
  float cntv = 0.f;
  for (int r = 0; r < NREP; ++r) cntv += gcnt[r*16 + c];
  float contrib = S*S / fmaxf(cntv, 1.f);
  for (int off = 32; off; off >>= 1) contrib += __shfl_down(contrib, off);
  __shared__ float red[4];
  if ((threadIdx.x & 63) == 0) red[threadIdx.x >> 6] = contrib;
  __syncthreads();
  if (threadIdx.x == 0) atomicAdd(&scal[SCAL_VAR], red[0]+red[1]+red[2]+red[3]);
}

__global__ void k_final(const float* __restrict__ scal, float* __restrict__ out){
  if (threadIdx.x == 0 && blockIdx.x == 0){
    float sumsq=0.f, ce=0.f, acc=0.f, l1=0.f;
    for (int r=0;r<NREP;++r){
      sumsq += scal[SCAL_SUMSQ+r];
      ce    += scal[SCAL_CE+r];
      acc   += scal[SCAL_ACC+r];
      l1    += scal[SCAL_L1+r];
    }
    float var_loss = sumsq - scal[SCAL_VAR];
    float loss = ce/(float)BATCH + 1e-4f*l1 + 1e-3f*var_loss;
    out[0] = loss;
    out[1] = acc/(float)BATCH;
  }
}

extern "C" void kernel_launch(void* const* d_in, const int* in_sizes, int n_in,
                              void* d_out, int out_size, void* d_ws, size_t ws_size,
                              hipStream_t stream){
  (void)in_sizes; (void)n_in; (void)out_size; (void)ws_size;
  const float* x   = (const float*)d_in[0];
  const int*   y   = (const int*)d_in[1];
  const float* fc0 = (const float*)d_in[2];
  const float* fc1 = (const float*)d_in[3];
  const float* w   = (const float*)d_in[4];
  const float* w1  = (const float*)d_in[5];
  char* ws = (char*)d_ws;
  unsigned short* fc0T = (unsigned short*)(ws + OFF_FC0T);
  unsigned short* fc1T = (unsigned short*)(ws + OFF_FC1T);
  unsigned short* wT   = (unsigned short*)(ws + OFF_WT);
  unsigned short* xT   = (unsigned short*)(ws + OFF_XT);
  unsigned short* x4T  = (unsigned short*)(ws + OFF_X4T);
  unsigned short* h    = (unsigned short*)(ws + OFF_XT);  // aliases xT (dead after gemm12)
  float* accb = (float*)(ws + OFF_ACC);
  float* scal = accb;
  float* gcnt = accb + CNT_OFF;
  float* gsum = accb + GSUM_OFF;

  k_zero<<<161, 512, 0, stream>>>(accb, ACC_FLOATS);
  k_prep<<<322, 256, 0, stream>>>(fc0, fc1, w, w1, fc0T, fc1T, wT, scal);
  k_xcast<<<1024, 256, 0, stream>>>(x, xT);
  k_gemm12<<<4096, 256, 0, stream>>>(xT, fc0T, fc1T, x4T, scal);
  k_csum<<<256, 256, 0, stream>>>(x4T, y, gsum);
  k_gemm3<<<512, 512, 0, stream>>>(x4T, wT, h);
  k_head<<<256, 256, 0, stream>>>(h, y, w1, scal, gcnt);
  k_reduce<<<20, 256, 0, stream>>>(gsum, gcnt, scal);
  k_final<<<1, 64, 0, stream>>>(scal, (float*)d_out);
}